// Round 2
// baseline (1507.927 us; speedup 1.0000x reference)
//
#include <hip/hip_runtime.h>
#include <hip/hip_bf16.h>

// AudioLSTM fused persistent kernel, v10: MFMA-BATCHED, 16 ELEMS/BLOCK.
// (Resubmission — previous round was an infra failure, no signal.)
// B=512, T=1000, IN=26, H1=64, H2=32, FC 32->16->10.
// 32 blocks x 256 threads (4 waves), 16 batch elems per block.
// All recurrent matvecs become mfma_f32_16x16x32_f16 with N=16 batch columns:
//   LSTM1: wave w owns gate-tiles {w,w+4,w+8,w+12} -> lane holds i,f,g,o of
//          units 16w+4*(lane>>4)..+3 for elem lane&15; c1 in regs.
//   xg[s+1] = W_ih1 @ X[s+1] computed same-wave into the same C layout and
//          used directly as C-init of the next hh-chain (bias in C-init).
//   LSTM2 (waves 0,1, one step behind): W_ih2 reuses the same h1 B-frags.
// x chunk-staged (16 steps) to LDS; h1/h2 handoff = 8B write + b128 reads.
// One barrier per step. f16 storage/mul, f32 accumulate (same as v9).

typedef __hip_bfloat16 bf16;
typedef _Float16 f16;
typedef _Float16 f16x8 __attribute__((ext_vector_type(8)));
typedef _Float16 f16x4 __attribute__((ext_vector_type(4)));
typedef float    f32x4 __attribute__((ext_vector_type(4)));

#define T_STEPS 1000
#define IN_DIM  26
#define EPB     16      // batch elems per block
#define CH      16      // staged x chunk length (timesteps)
#define H1P     72      // padded h1 row (f16): 144B rows, 16B-aligned
#define H2P     40      // padded h2 row (f16): 80B rows

__device__ __forceinline__ float bits2f(unsigned short h) {
    return __uint_as_float(((unsigned int)h) << 16);
}
__device__ __forceinline__ float ldv(const void* p, long i, bool isb) {
    return isb ? bits2f(((const unsigned short*)p)[i]) : ((const float*)p)[i];
}
__device__ __forceinline__ float rcp_(float x) { return __builtin_amdgcn_rcpf(x); }
__device__ __forceinline__ float sigm(float x) {
    return rcp_(1.0f + __expf(-x));
}
__device__ __forceinline__ float tanh_(float x) {
    float a = fabsf(x);
    float r = 1.0f - 2.0f * rcp_(__expf(2.0f * a) + 1.0f);
    return copysignf(r, x);
}
#define MFMA(a, b, c) __builtin_amdgcn_mfma_f32_16x16x32_f16((a), (b), (c), 0, 0, 0)

__global__
__attribute__((amdgpu_flat_work_group_size(256, 256), amdgpu_waves_per_eu(1, 1)))
void lstm_fused(const void* __restrict__ x,
                const void* __restrict__ w_ih1, const void* __restrict__ w_hh1,
                const void* __restrict__ b_ih1, const void* __restrict__ b_hh1,
                const void* __restrict__ w_ih2, const void* __restrict__ w_hh2,
                const void* __restrict__ b_ih2, const void* __restrict__ b_hh2,
                const void* __restrict__ w_fc1, const void* __restrict__ b_fc1,
                const void* __restrict__ w_fc2, const void* __restrict__ b_fc2,
                void* __restrict__ out)
{
    const int tid  = threadIdx.x;      // 0..255
    const int lane = tid & 63;
    const int wv   = tid >> 6;         // wave 0..3
    const int ecol = lane & 15;        // MFMA N-col = elem within block
    const int g4   = lane >> 4;        // lane group 0..3
    const int e0   = blockIdx.x * EPB;

    __shared__ __align__(16) f16  Xst[2][CH][EPB][32];  // x chunk, k-pad 26..31 = 0
    __shared__ __align__(16) f16  H1T[2][EPB][H1P];     // h1, dbuf by parity
    __shared__ __align__(16) f16  H2T[2][EPB][H2P];     // h2, dbuf by parity
    __shared__ __align__(16) float f1s[EPB][16];

    // ---- runtime dtype detection (uniform): w_ih1 ~ U(-1/8,1/8) ----
    bool isb = true;
    {
        const unsigned short* wu = (const unsigned short*)w_ih1;
        for (int k = 0; k < 64; ++k) {
            float v = fabsf(bits2f(wu[k]));
            if (!(v <= 0.1251f)) isb = false;
        }
    }

    // ---- zero LDS (zeros double as: x k-pad, h pads, h1[-1]=h2[-1]=0) ----
    {
        float4 z; z.x = z.y = z.z = z.w = 0.f;
        float4* p = (float4*)&Xst[0][0][0][0];
        for (int k = tid; k < (int)(sizeof(Xst) / 16); k += 256) p[k] = z;
        float4* q = (float4*)&H1T[0][0][0];
        for (int k = tid; k < (int)(sizeof(H1T) / 16); k += 256) q[k] = z;
        float4* r = (float4*)&H2T[0][0][0];
        for (int k = tid; k < (int)(sizeof(H2T) / 16); k += 256) r[k] = z;
    }

    // ---- weight fragments (A-frag: row = lane&15, k = 8*(lane>>4)+j) ----
    const int r15 = lane & 15;
    f16x8 Whh1A[4][2], Wih1A[4];
    f32x4 b1C[4];                       // bias as MFMA C-init (row = 4*g4+j)
#pragma unroll
    for (int gi = 0; gi < 4; ++gi) {    // gate gi: rows gi*64 + [16wv,16wv+16)
        const int R = gi * 64 + 16 * wv + r15;
#pragma unroll
        for (int k0 = 0; k0 < 2; ++k0)
#pragma unroll
            for (int jj = 0; jj < 8; ++jj)
                Whh1A[gi][k0][jj] =
                    (f16)ldv(w_hh1, R * 64 + k0 * 32 + g4 * 8 + jj, isb);
#pragma unroll
        for (int jj = 0; jj < 8; ++jj) {
            const int k = g4 * 8 + jj;
            Wih1A[gi][jj] = (f16)(k < IN_DIM ? ldv(w_ih1, R * IN_DIM + k, isb) : 0.f);
        }
#pragma unroll
        for (int jj = 0; jj < 4; ++jj) {
            const int Rc = gi * 64 + 16 * wv + g4 * 4 + jj;
            b1C[gi][jj] = ldv(b_ih1, Rc, isb) + ldv(b_hh1, Rc, isb);
        }
    }
    f16x8 Wih2A[4][2], Whh2A[4];
    f32x4 b2C[4];
    if (wv < 2) {                       // LSTM2: gate gi rows gi*32 + [16wv,16wv+16)
#pragma unroll
        for (int gi = 0; gi < 4; ++gi) {
            const int R = gi * 32 + 16 * wv + r15;
#pragma unroll
            for (int k0 = 0; k0 < 2; ++k0)
#pragma unroll
                for (int jj = 0; jj < 8; ++jj)
                    Wih2A[gi][k0][jj] =
                        (f16)ldv(w_ih2, R * 64 + k0 * 32 + g4 * 8 + jj, isb);
#pragma unroll
            for (int jj = 0; jj < 8; ++jj)
                Whh2A[gi][jj] = (f16)ldv(w_hh2, R * 32 + g4 * 8 + jj, isb);
#pragma unroll
            for (int jj = 0; jj < 4; ++jj) {
                const int Rc = gi * 32 + 16 * wv + g4 * 4 + jj;
                b2C[gi][jj] = ldv(b_ih2, Rc, isb) + ldv(b_hh2, Rc, isb);
            }
        }
    }

    __syncthreads();   // LDS zeroed before staging overwrites k<26

    // stage chunk c: Xst[c&1][t][e][i] = x[e0+e][i][c*CH+t]  (B-frag layout)
    auto stage = [&](int c) {
        const int bf = c & 1, t0 = c * CH;
        const int nt = (T_STEPS - t0 < CH) ? (T_STEPS - t0) : CH;
        for (int p = tid; p < EPB * IN_DIM; p += 256) {
            const int e = p / IN_DIM, i = p - e * IN_DIM;
            const long gb = ((long)(e0 + e) * IN_DIM + i) * T_STEPS + t0;
            for (int t = 0; t < nt; ++t)
                Xst[bf][t][e][i] = (f16)ldv(x, gb + t, isb);
        }
    };
    stage(0);
    __syncthreads();

    // xg[0] into registers (C-layout, bias folded in)
    f32x4 xgc[4];
    {
        const f16x8 xf = *(const f16x8*)&Xst[0][0][ecol][g4 * 8];
#pragma unroll
        for (int gi = 0; gi < 4; ++gi) xgc[gi] = MFMA(Wih1A[gi], xf, b1C[gi]);
    }

    float c1[4] = {0.f, 0.f, 0.f, 0.f};
    float c2[4] = {0.f, 0.f, 0.f, 0.f};

    for (int s = 0; s <= T_STEPS; ++s) {
        const int pc = s & 1, pp = pc ^ 1;
        // h1[s-1] B-frags (B-frag: col = lane&15, k = 8*(lane>>4)+j);
        // shared by LSTM1 hh-chain and LSTM2 ih-chain.
        const f16x8 h1f0 = *(const f16x8*)&H1T[pp][ecol][g4 * 8];
        const f16x8 h1f1 = *(const f16x8*)&H1T[pp][ecol][32 + g4 * 8];

        // ---- LSTM1 step s (all waves) ----
        if (s < T_STEPS) {
            f32x4 gt[4];
#pragma unroll
            for (int gi = 0; gi < 4; ++gi) {
                f32x4 t0 = MFMA(Whh1A[gi][0], h1f0, xgc[gi]);   // C-init = xg+bias
                gt[gi]   = MFMA(Whh1A[gi][1], h1f1, t0);
            }
            // xg[s+1] (independent; overlaps the nonlinearity below)
            if (s + 1 < T_STEPS) {
                const int sn = s + 1;
                const f16x8 xf =
                    *(const f16x8*)&Xst[(sn >> 4) & 1][sn & 15][ecol][g4 * 8];
#pragma unroll
                for (int gi = 0; gi < 4; ++gi) xgc[gi] = MFMA(Wih1A[gi], xf, b1C[gi]);
            }
            f16x4 hh;
#pragma unroll
            for (int jj = 0; jj < 4; ++jj) {          // unit 16wv + 4*g4 + jj
                const float ii = sigm(gt[0][jj]);
                const float ff = sigm(gt[1][jj]);
                const float gg = tanh_(gt[2][jj]);
                const float oo = sigm(gt[3][jj]);
                c1[jj] = fmaf(ff, c1[jj], ii * gg);
                hh[jj] = (f16)(oo * tanh_(c1[jj]));
            }
            *(f16x4*)&H1T[pc][ecol][16 * wv + g4 * 4] = hh;   // 8B aligned
        }

        // ---- LSTM2 step s-1 (waves 0,1): in = h1[s-1], state h2[s-2] ----
        if (wv < 2 && s >= 1) {
            const f16x8 h2f = *(const f16x8*)&H2T[pc][ecol][g4 * 8];  // h2[s-2]
            f32x4 gt[4];
#pragma unroll
            for (int gi = 0; gi < 4; ++gi) {
                f32x4 t0 = MFMA(Wih2A[gi][0], h1f0, b2C[gi]);
                t0       = MFMA(Wih2A[gi][1], h1f1, t0);
                gt[gi]   = MFMA(Whh2A[gi], h2f, t0);
            }
            f16x4 hh;
#pragma unroll
            for (int jj = 0; jj < 4; ++jj) {          // unit 16wv + 4*g4 + jj
                const float ii = sigm(gt[0][jj]);
                const float ff = sigm(gt[1][jj]);
                const float gg = tanh_(gt[2][jj]);
                const float oo = sigm(gt[3][jj]);
                c2[jj] = fmaf(ff, c2[jj], ii * gg);
                hh[jj] = (f16)(oo * tanh_(c2[jj]));
            }
            *(f16x4*)&H2T[pp][ecol][16 * wv + g4 * 4] = hh;   // h2[s-1]
        }

        // ---- stage next x chunk once per CH steps ----
        if ((s & (CH - 1)) == 0 && s + CH < T_STEPS) stage((s >> 4) + 1);

        __syncthreads();
    }

    // ---- FC head: h2[T-1] lives in H2T[(T-1)&1] = H2T[1] ----
    {
        const int e = tid >> 4, o = tid & 15;   // all 256 threads: one (e,f1-out)
        float ss = ldv(b_fc1, o, isb);
#pragma unroll 8
        for (int k = 0; k < 32; ++k)
            ss = fmaf(ldv(w_fc1, o * 32 + k, isb), (float)H2T[1][e][k], ss);
        f1s[e][o] = fmaxf(ss, 0.f);
    }
    __syncthreads();
    if (tid < EPB * 10) {
        const int e = tid / 10, o = tid - e * 10;
        float ss = ldv(b_fc2, o, isb);
#pragma unroll
        for (int k = 0; k < 16; ++k)
            ss = fmaf(ldv(w_fc2, o * 16 + k, isb), f1s[e][k], ss);
        const long oi = (long)(e0 + e) * 10 + o;
        if (isb) ((bf16*)out)[oi] = __float2bfloat16(ss);
        else     ((float*)out)[oi] = ss;
    }
}

extern "C" void kernel_launch(void* const* d_in, const int* in_sizes, int n_in,
                              void* d_out, int out_size, void* d_ws, size_t ws_size,
                              hipStream_t stream) {
    lstm_fused<<<dim3(512 / EPB), dim3(256), 0, stream>>>(
        d_in[0], d_in[1], d_in[2], d_in[3], d_in[4],
        d_in[5], d_in[6], d_in[7], d_in[8],
        d_in[9], d_in[10], d_in[11], d_in[12], d_out);
}

// Round 3
// 1421.146 us; speedup vs baseline: 1.0611x; 1.0611x over previous
//
#include <hip/hip_runtime.h>
#include <hip/hip_bf16.h>

// AudioLSTM fused persistent kernel, v11: MFMA-BATCHED + CHEAP ACTIVATIONS.
// B=512, T=1000, IN=26, H1=64, H2=32, FC 32->16->10.
// 32 blocks x 256 threads (4 waves), 16 batch elems per block (v10 structure).
// v10 post-mortem: 1417us, crit-wave bound by activation issue (8 units/lane
// x ~10 quarter-rate trans + ~24 VALU glue) + exposed MFMA/LDS latency.
// v11: (1) fold -log2e (i,f,o) / -2log2e (g) into weight rows + biases so
//      sigm(x)=rcp(1+exp2(y)), tanh(g)=(2-b1)/b1 -- no muls/fabs/copysign;
//      (2) pair-rcp: i*g=(2-b1)*rcp(a1*b1), o*tanh(c)=(2-c1p)*rcp(o1*c1p)
//      -> 8 trans + ~13 VALU per unit (exact algebra, was 10 + ~24);
//      (3) hoist h1/h2/x LDS reads to iter top; all MFMAs before all acts
//      so matrix-pipe latency drains under activation issue.

typedef __hip_bfloat16 bf16;
typedef _Float16 f16;
typedef _Float16 f16x8 __attribute__((ext_vector_type(8)));
typedef _Float16 f16x4 __attribute__((ext_vector_type(4)));
typedef float    f32x4 __attribute__((ext_vector_type(4)));

#define T_STEPS 1000
#define IN_DIM  26
#define EPB     16      // batch elems per block
#define CH      16      // staged x chunk length (timesteps)
#define H1P     72      // padded h1 row (f16)
#define H2P     40      // padded h2 row (f16)

#define NL2E  -1.4426950408889634f   // -log2(e): i,f,o gate prescale
#define N2L2E -2.8853900817779268f   // -2log2(e): g gate prescale

__device__ __forceinline__ float bits2f(unsigned short h) {
    return __uint_as_float(((unsigned int)h) << 16);
}
__device__ __forceinline__ float ldv(const void* p, long i, bool isb) {
    return isb ? bits2f(((const unsigned short*)p)[i]) : ((const float*)p)[i];
}
__device__ __forceinline__ float rcp_(float x) { return __builtin_amdgcn_rcpf(x); }
__device__ __forceinline__ float ex2_(float x) { return __builtin_amdgcn_exp2f(x); }

// yi,yf,yg,yo are PRESCALED pre-activations (yi=-log2e*pi, yg=-2log2e*pg, ...).
// Updates c, returns h = sigm(o)*tanh(c).  8 trans + ~13 VALU, branch-free.
__device__ __forceinline__ float lstm_act(float yi, float yf, float yg,
                                          float yo, float& c) {
    const float A  = ex2_(yi), F = ex2_(yf), B = ex2_(yg), O = ex2_(yo);
    const float a1 = 1.f + A, f1 = 1.f + F, b1 = 1.f + B, o1 = 1.f + O;
    const float ig = (2.f - b1) * rcp_(a1 * b1);     // sigm(i)*tanh(g)
    c = fmaf(rcp_(f1), c, ig);                       // f*c + i*g
    const float C2  = ex2_(N2L2E * c);               // e^(-2c)
    const float c1p = 1.f + C2;
    return (2.f - c1p) * rcp_(o1 * c1p);             // sigm(o)*tanh(c)
}

#define MFMA(a, b, c) __builtin_amdgcn_mfma_f32_16x16x32_f16((a), (b), (c), 0, 0, 0)

__global__
__attribute__((amdgpu_flat_work_group_size(256, 256), amdgpu_waves_per_eu(1, 1)))
void lstm_fused(const void* __restrict__ x,
                const void* __restrict__ w_ih1, const void* __restrict__ w_hh1,
                const void* __restrict__ b_ih1, const void* __restrict__ b_hh1,
                const void* __restrict__ w_ih2, const void* __restrict__ w_hh2,
                const void* __restrict__ b_ih2, const void* __restrict__ b_hh2,
                const void* __restrict__ w_fc1, const void* __restrict__ b_fc1,
                const void* __restrict__ w_fc2, const void* __restrict__ b_fc2,
                void* __restrict__ out)
{
    const int tid  = threadIdx.x;      // 0..255
    const int lane = tid & 63;
    const int wv   = tid >> 6;         // wave 0..3
    const int ecol = lane & 15;        // MFMA N-col = elem within block
    const int g4   = lane >> 4;        // lane group 0..3
    const int e0   = blockIdx.x * EPB;

    __shared__ __align__(16) f16  Xst[2][CH][EPB][32];  // x chunk, k-pad 26..31 = 0
    __shared__ __align__(16) f16  H1T[2][EPB][H1P];     // h1, dbuf by parity
    __shared__ __align__(16) f16  H2T[2][EPB][H2P];     // h2, dbuf by parity
    __shared__ __align__(16) float f1s[EPB][16];

    // ---- runtime dtype detection (uniform): w_ih1 ~ U(-1/8,1/8) ----
    bool isb = true;
    {
        const unsigned short* wu = (const unsigned short*)w_ih1;
        for (int k = 0; k < 64; ++k) {
            float v = fabsf(bits2f(wu[k]));
            if (!(v <= 0.1251f)) isb = false;
        }
    }

    // ---- zero LDS (zeros double as: x k-pad, h pads, h1[-1]=h2[-1]=0) ----
    {
        float4 z; z.x = z.y = z.z = z.w = 0.f;
        float4* p = (float4*)&Xst[0][0][0][0];
        for (int k = tid; k < (int)(sizeof(Xst) / 16); k += 256) p[k] = z;
        float4* q = (float4*)&H1T[0][0][0];
        for (int k = tid; k < (int)(sizeof(H1T) / 16); k += 256) q[k] = z;
        float4* r = (float4*)&H2T[0][0][0];
        for (int k = tid; k < (int)(sizeof(H2T) / 16); k += 256) r[k] = z;
    }

    // ---- weight fragments (A-frag: row = lane&15, k = 8*(lane>>4)+j) ----
    // Gate prescale folded in: rows of gate g get -2log2e, others -log2e.
    const int r15 = lane & 15;
    f16x8 Whh1A[4][2], Wih1A[4];
    f32x4 b1C[4];                       // bias as MFMA C-init (row = 4*g4+j)
#pragma unroll
    for (int gi = 0; gi < 4; ++gi) {    // gate gi: rows gi*64 + [16wv,16wv+16)
        const float sc = (gi == 2) ? N2L2E : NL2E;
        const int R = gi * 64 + 16 * wv + r15;
#pragma unroll
        for (int k0 = 0; k0 < 2; ++k0)
#pragma unroll
            for (int jj = 0; jj < 8; ++jj)
                Whh1A[gi][k0][jj] =
                    (f16)(sc * ldv(w_hh1, R * 64 + k0 * 32 + g4 * 8 + jj, isb));
#pragma unroll
        for (int jj = 0; jj < 8; ++jj) {
            const int k = g4 * 8 + jj;
            Wih1A[gi][jj] =
                (f16)(k < IN_DIM ? sc * ldv(w_ih1, R * IN_DIM + k, isb) : 0.f);
        }
#pragma unroll
        for (int jj = 0; jj < 4; ++jj) {
            const int Rc = gi * 64 + 16 * wv + g4 * 4 + jj;
            b1C[gi][jj] = sc * (ldv(b_ih1, Rc, isb) + ldv(b_hh1, Rc, isb));
        }
    }
    f16x8 Wih2A[4][2], Whh2A[4];
    f32x4 b2C[4];
    if (wv < 2) {                       // LSTM2: gate gi rows gi*32 + [16wv,16wv+16)
#pragma unroll
        for (int gi = 0; gi < 4; ++gi) {
            const float sc = (gi == 2) ? N2L2E : NL2E;
            const int R = gi * 32 + 16 * wv + r15;
#pragma unroll
            for (int k0 = 0; k0 < 2; ++k0)
#pragma unroll
                for (int jj = 0; jj < 8; ++jj)
                    Wih2A[gi][k0][jj] =
                        (f16)(sc * ldv(w_ih2, R * 64 + k0 * 32 + g4 * 8 + jj, isb));
#pragma unroll
            for (int jj = 0; jj < 8; ++jj)
                Whh2A[gi][jj] = (f16)(sc * ldv(w_hh2, R * 32 + g4 * 8 + jj, isb));
#pragma unroll
            for (int jj = 0; jj < 4; ++jj) {
                const int Rc = gi * 32 + 16 * wv + g4 * 4 + jj;
                b2C[gi][jj] = sc * (ldv(b_ih2, Rc, isb) + ldv(b_hh2, Rc, isb));
            }
        }
    }

    __syncthreads();   // LDS zeroed before staging overwrites k<26

    // stage chunk c: Xst[c&1][t][e][i] = x[e0+e][i][c*CH+t]  (B-frag layout)
    auto stage = [&](int c) {
        const int bf = c & 1, t0 = c * CH;
        const int nt = (T_STEPS - t0 < CH) ? (T_STEPS - t0) : CH;
        for (int p = tid; p < EPB * IN_DIM; p += 256) {
            const int e = p / IN_DIM, i = p - e * IN_DIM;
            const long gb = ((long)(e0 + e) * IN_DIM + i) * T_STEPS + t0;
            for (int t = 0; t < nt; ++t)
                Xst[bf][t][e][i] = (f16)ldv(x, gb + t, isb);
        }
    };
    stage(0);
    __syncthreads();

    // xg[0] into registers (C-layout, prescaled bias folded in)
    f32x4 xgc[4];
    {
        const f16x8 xf = *(const f16x8*)&Xst[0][0][ecol][g4 * 8];
#pragma unroll
        for (int gi = 0; gi < 4; ++gi) xgc[gi] = MFMA(Wih1A[gi], xf, b1C[gi]);
    }

    float c1[4] = {0.f, 0.f, 0.f, 0.f};
    float c2[4] = {0.f, 0.f, 0.f, 0.f};

    for (int s = 0; s <= T_STEPS; ++s) {
        const int pc = s & 1, pp = pc ^ 1;

        // ---- hoisted LDS reads: issue all b128s together at iter top ----
        const f16x8 h1f0 = *(const f16x8*)&H1T[pp][ecol][g4 * 8];
        const f16x8 h1f1 = *(const f16x8*)&H1T[pp][ecol][32 + g4 * 8];
        f16x8 h2f = {};
        if (wv < 2) h2f = *(const f16x8*)&H2T[pc][ecol][g4 * 8];   // h2[s-2]
        f16x8 xf = {};
        if (s + 1 < T_STEPS) {
            const int sn = s + 1;
            xf = *(const f16x8*)&Xst[(sn >> 4) & 1][sn & 15][ecol][g4 * 8];
        }

        // ---- all MFMA blocks first (latency drains under activations) ----
        f32x4 gt1[4], gt2[4];
        if (s < T_STEPS) {
#pragma unroll
            for (int gi = 0; gi < 4; ++gi) {
                f32x4 t0 = MFMA(Whh1A[gi][0], h1f0, xgc[gi]);   // C-init = xg+bias
                gt1[gi]  = MFMA(Whh1A[gi][1], h1f1, t0);
            }
        }
        if (wv < 2 && s >= 1) {
#pragma unroll
            for (int gi = 0; gi < 4; ++gi) {
                f32x4 t0 = MFMA(Wih2A[gi][0], h1f0, b2C[gi]);
                t0       = MFMA(Wih2A[gi][1], h1f1, t0);
                gt2[gi]  = MFMA(Whh2A[gi], h2f, t0);
            }
        }
        if (s + 1 < T_STEPS) {          // xg[s+1]; overwrites xgc AFTER gt1 use
#pragma unroll
            for (int gi = 0; gi < 4; ++gi) xgc[gi] = MFMA(Wih1A[gi], xf, b1C[gi]);
        }

        // ---- stage next x chunk (every CH steps); overlaps activations ----
        if ((s & (CH - 1)) == 0 && s + CH < T_STEPS) stage((s >> 4) + 1);

        // ---- activations ----
        if (s < T_STEPS) {
            f16x4 hh;
#pragma unroll
            for (int jj = 0; jj < 4; ++jj)            // unit 16wv + 4*g4 + jj
                hh[jj] = (f16)lstm_act(gt1[0][jj], gt1[1][jj],
                                       gt1[2][jj], gt1[3][jj], c1[jj]);
            *(f16x4*)&H1T[pc][ecol][16 * wv + g4 * 4] = hh;   // 8B aligned
        }
        if (wv < 2 && s >= 1) {
            f16x4 hh;
#pragma unroll
            for (int jj = 0; jj < 4; ++jj)            // unit 16wv + 4*g4 + jj
                hh[jj] = (f16)lstm_act(gt2[0][jj], gt2[1][jj],
                                       gt2[2][jj], gt2[3][jj], c2[jj]);
            *(f16x4*)&H2T[pp][ecol][16 * wv + g4 * 4] = hh;   // h2[s-1]
        }

        __syncthreads();
    }

    // ---- FC head: h2[T-1] lives in H2T[(T-1)&1] = H2T[1] ----
    {
        const int e = tid >> 4, o = tid & 15;   // all 256 threads: one (e,f1-out)
        float ss = ldv(b_fc1, o, isb);
#pragma unroll 8
        for (int k = 0; k < 32; ++k)
            ss = fmaf(ldv(w_fc1, o * 32 + k, isb), (float)H2T[1][e][k], ss);
        f1s[e][o] = fmaxf(ss, 0.f);
    }
    __syncthreads();
    if (tid < EPB * 10) {
        const int e = tid / 10, o = tid - e * 10;
        float ss = ldv(b_fc2, o, isb);
#pragma unroll
        for (int k = 0; k < 16; ++k)
            ss = fmaf(ldv(w_fc2, o * 16 + k, isb), f1s[e][k], ss);
        const long oi = (long)(e0 + e) * 10 + o;
        if (isb) ((bf16*)out)[oi] = __float2bfloat16(ss);
        else     ((float*)out)[oi] = ss;
    }
}

extern "C" void kernel_launch(void* const* d_in, const int* in_sizes, int n_in,
                              void* d_out, int out_size, void* d_ws, size_t ws_size,
                              hipStream_t stream) {
    lstm_fused<<<dim3(512 / EPB), dim3(256), 0, stream>>>(
        d_in[0], d_in[1], d_in[2], d_in[3], d_in[4],
        d_in[5], d_in[6], d_in[7], d_in[8],
        d_in[9], d_in[10], d_in[11], d_in[12], d_out);
}

// Round 4
// 1335.876 us; speedup vs baseline: 1.1288x; 1.0638x over previous
//
#include <hip/hip_runtime.h>
#include <hip/hip_bf16.h>

// AudioLSTM fused persistent kernel, v12: MFMA + TLP PAIRING + WIDE STAGING.
// B=512, T=1000, IN=26, H1=64, H2=32, FC 32->16->10.
// 16 blocks x 512 threads (8 waves) = 2 batch-groups of 16 elems per block.
// v11 post-mortem: time is stall-bound, not issue-bound (VALU cut -14%, dur
// -1.4%). Stalls = (a) serialized scalar x-staging (runtime-bound inner loop
// -> load;wait;write x32 per thread every 16 steps, barrier-coupled), (b) one
// wave/SIMD => zero latency hiding, (c) Xst 8-way bank conflict (2.56M).
// v12: (a) wide b128 staging, split issue-early/write-late (T14) so HBM
//      latency hides under compute; (b) 2 groups/block, role map
//      (wv&3)^((wv&4)>>1) pairs heavy(LSTM1+LSTM2) with light waves on each
//      SIMD for TLP; (c) Xst row pad 32->40 f16 (80B stride, <=2-way free).
// Math identical to v11: f16 MFMA, prescaled gates, pair-rcp activations.

typedef __hip_bfloat16 bf16;
typedef _Float16 f16;
typedef _Float16 f16x8 __attribute__((ext_vector_type(8)));
typedef _Float16 f16x4 __attribute__((ext_vector_type(4)));
typedef float    f32x4 __attribute__((ext_vector_type(4)));

#define T_STEPS 1000
#define IN_DIM  26
#define EPB     16      // batch elems per group
#define CH      16      // staged x chunk length (timesteps)
#define H1P     72      // padded h1 row (f16)
#define H2P     40      // padded h2 row (f16)
#define XP      40      // padded Xst row (f16): 80B stride -> <=2-way banks

#define NL2E  -1.4426950408889634f   // -log2(e): i,f,o gate prescale
#define N2L2E -2.8853900817779268f   // -2log2(e): g gate prescale

__device__ __forceinline__ float bits2f(unsigned short h) {
    return __uint_as_float(((unsigned int)h) << 16);
}
__device__ __forceinline__ float ldv(const void* p, long i, bool isb) {
    return isb ? bits2f(((const unsigned short*)p)[i]) : ((const float*)p)[i];
}
__device__ __forceinline__ float rcp_(float x) { return __builtin_amdgcn_rcpf(x); }
__device__ __forceinline__ float ex2_(float x) { return __builtin_amdgcn_exp2f(x); }

// Prescaled pre-activations (yi=-log2e*pi, yg=-2log2e*pg, ...).
// Updates c, returns h = sigm(o)*tanh(c). 5 exp2 + 3 rcp + ~13 VALU.
__device__ __forceinline__ float lstm_act(float yi, float yf, float yg,
                                          float yo, float& c) {
    const float A  = ex2_(yi), F = ex2_(yf), B = ex2_(yg), O = ex2_(yo);
    const float a1 = 1.f + A, f1 = 1.f + F, b1 = 1.f + B, o1 = 1.f + O;
    const float ig = (2.f - b1) * rcp_(a1 * b1);     // sigm(i)*tanh(g)
    c = fmaf(rcp_(f1), c, ig);                       // f*c + i*g
    const float C2  = ex2_(N2L2E * c);               // e^(-2c)
    const float c1p = 1.f + C2;
    return (2.f - c1p) * rcp_(o1 * c1p);             // sigm(o)*tanh(c)
}

#define MFMA(a, b, c) __builtin_amdgcn_mfma_f32_16x16x32_f16((a), (b), (c), 0, 0, 0)

__global__
__attribute__((amdgpu_flat_work_group_size(512, 512), amdgpu_waves_per_eu(2, 2)))
void lstm_fused(const void* __restrict__ x,
                const void* __restrict__ w_ih1, const void* __restrict__ w_hh1,
                const void* __restrict__ b_ih1, const void* __restrict__ b_hh1,
                const void* __restrict__ w_ih2, const void* __restrict__ w_hh2,
                const void* __restrict__ b_ih2, const void* __restrict__ b_hh2,
                const void* __restrict__ w_fc1, const void* __restrict__ b_fc1,
                const void* __restrict__ w_fc2, const void* __restrict__ b_fc2,
                void* __restrict__ out)
{
    const int tid  = threadIdx.x;      // 0..511
    const int lane = tid & 63;
    const int wv   = tid >> 6;         // 0..7
    const int grp  = wv >> 2;          // batch-group within block
    // role: 0,1 = heavy (LSTM1+LSTM2), 2,3 = light (LSTM1 only).
    // Mapping pairs heavy+light on each SIMD (SIMD = wv&3).
    const int role = (wv & 3) ^ ((wv & 4) >> 1);
    const int ecol = lane & 15;        // MFMA N-col = elem within group
    const int g4   = lane >> 4;        // lane group 0..3
    const int r15  = lane & 15;
    const int eblk = blockIdx.x * (2 * EPB);
    const int e0   = eblk + grp * EPB;

    __shared__ __align__(16) f16  Xst[2][2][CH][EPB][XP]; // [grp][buf][t][e][i]
    __shared__ __align__(16) f16  H1T[2][2][EPB][H1P];    // [grp][parity][e][..]
    __shared__ __align__(16) f16  H2T[2][2][EPB][H2P];
    __shared__ __align__(16) float f1s[2][EPB][16];

    // ---- runtime dtype detection (uniform): w_ih1 ~ U(-1/8,1/8) ----
    bool isb = true;
    {
        const unsigned short* wu = (const unsigned short*)w_ih1;
        for (int k = 0; k < 64; ++k) {
            float v = fabsf(bits2f(wu[k]));
            if (!(v <= 0.1251f)) isb = false;
        }
    }

    // ---- zero LDS (x k-pad, h pads, h1[-1]=h2[-1]=0) ----
    {
        float4 z; z.x = z.y = z.z = z.w = 0.f;
        float4* p = (float4*)&Xst[0][0][0][0][0];
        for (int k = tid; k < (int)(sizeof(Xst) / 16); k += 512) p[k] = z;
        float4* q = (float4*)&H1T[0][0][0][0];
        for (int k = tid; k < (int)(sizeof(H1T) / 16); k += 512) q[k] = z;
        float4* r = (float4*)&H2T[0][0][0][0];
        for (int k = tid; k < (int)(sizeof(H2T) / 16); k += 512) r[k] = z;
    }

    // ---- weight fragments (A-frag: row = lane&15, k = 8*(lane>>4)+j) ----
    // Gate prescale folded: gate g rows x -2log2e, others x -log2e.
    f16x8 Whh1A[4][2], Wih1A[4];
    f32x4 b1C[4];
#pragma unroll
    for (int gi = 0; gi < 4; ++gi) {    // gate gi rows gi*64 + [16*role, +16)
        const float sc = (gi == 2) ? N2L2E : NL2E;
        const int R = gi * 64 + 16 * role + r15;
#pragma unroll
        for (int k0 = 0; k0 < 2; ++k0)
#pragma unroll
            for (int jj = 0; jj < 8; ++jj)
                Whh1A[gi][k0][jj] =
                    (f16)(sc * ldv(w_hh1, R * 64 + k0 * 32 + g4 * 8 + jj, isb));
#pragma unroll
        for (int jj = 0; jj < 8; ++jj) {
            const int k = g4 * 8 + jj;
            Wih1A[gi][jj] =
                (f16)(k < IN_DIM ? sc * ldv(w_ih1, R * IN_DIM + k, isb) : 0.f);
        }
#pragma unroll
        for (int jj = 0; jj < 4; ++jj) {
            const int Rc = gi * 64 + 16 * role + g4 * 4 + jj;
            b1C[gi][jj] = sc * (ldv(b_ih1, Rc, isb) + ldv(b_hh1, Rc, isb));
        }
    }
    f16x8 Wih2A[4][2], Whh2A[4];
    f32x4 b2C[4];
    if (role < 2) {                     // LSTM2 gate gi rows gi*32 + [16*role,+16)
#pragma unroll
        for (int gi = 0; gi < 4; ++gi) {
            const float sc = (gi == 2) ? N2L2E : NL2E;
            const int R = gi * 32 + 16 * role + r15;
#pragma unroll
            for (int k0 = 0; k0 < 2; ++k0)
#pragma unroll
                for (int jj = 0; jj < 8; ++jj)
                    Wih2A[gi][k0][jj] =
                        (f16)(sc * ldv(w_ih2, R * 64 + k0 * 32 + g4 * 8 + jj, isb));
#pragma unroll
            for (int jj = 0; jj < 8; ++jj)
                Whh2A[gi][jj] = (f16)(sc * ldv(w_hh2, R * 32 + g4 * 8 + jj, isb));
#pragma unroll
            for (int jj = 0; jj < 4; ++jj) {
                const int Rc = gi * 32 + 16 * role + g4 * 4 + jj;
                b2C[gi][jj] = sc * (ldv(b_ih2, Rc, isb) + ldv(b_hh2, Rc, isb));
            }
        }
    }

    __syncthreads();   // LDS zeroed before staging overwrites i<26

    // ---- synchronous wide stage (prologue only), chunk c ----
    auto stageSync = [&](int c) {
        const int t0 = c * CH;
        const int nt = (T_STEPS - t0 < CH) ? (T_STEPS - t0) : CH;
        for (int p = tid; p < 2 * EPB * IN_DIM; p += 512) {
            const int g = (p >= EPB * IN_DIM) ? 1 : 0;
            const int rr = p - g * EPB * IN_DIM;
            const int el = rr / IN_DIM, ii = rr - IN_DIM * el;
            const long be = ((long)(eblk + g * EPB + el) * IN_DIM + ii) * T_STEPS + t0;
            float4 fb[4];
            if (isb) {
                const float4* q = (const float4*)((const unsigned short*)x + be);
                fb[0] = q[0]; if (nt > 8) fb[1] = q[1];
            } else {
                const float4* q = (const float4*)((const float*)x + be);
                fb[0] = q[0]; fb[1] = q[1];
                if (nt > 8) { fb[2] = q[2]; fb[3] = q[3]; }
            }
#pragma unroll
            for (int t = 0; t < CH; ++t) if (t < nt) {
                float v;
                if (isb) {
                    unsigned int u =
                        __builtin_bit_cast(unsigned int, fb[t >> 3][(t >> 1) & 3]);
                    v = bits2f((t & 1) ? (unsigned short)(u >> 16)
                                       : (unsigned short)(u & 0xffffu));
                } else {
                    v = fb[t >> 2][t & 3];
                }
                Xst[g][c & 1][t][el][ii] = (f16)v;
            }
        }
    };
    stageSync(0);
    __syncthreads();

    // xg[0] into registers (C-layout, prescaled bias folded in)
    f32x4 xgc[4];
    {
        const f16x8 xf = *(const f16x8*)&Xst[grp][0][0][ecol][g4 * 8];
#pragma unroll
        for (int gi = 0; gi < 4; ++gi) xgc[gi] = MFMA(Wih1A[gi], xf, b1C[gi]);
    }

    float c1[4] = {0.f, 0.f, 0.f, 0.f};
    float c2[4] = {0.f, 0.f, 0.f, 0.f};
    const bool hasB = (tid < 2 * EPB * IN_DIM - 512);   // tid < 320

    for (int s = 0; s <= T_STEPS; ++s) {
        const int pc = s & 1, pp = pc ^ 1;
        const bool doStage = ((s & (CH - 1)) == 0) && (s + CH < T_STEPS);

        // ---- stage loads issued EARLY (independent of compute) ----
        float4 fbA[4], fbB[4];
        int gA = 0, elA = 0, iiA = 0, gB = 0, elB = 0, iiB = 0, ntS = CH;
        if (doStage) {
            const int c = (s >> 4) + 1, t0 = c * CH;
            ntS = (T_STEPS - t0 < CH) ? (T_STEPS - t0) : CH;
            {
                const int p = tid;
                gA = (p >= EPB * IN_DIM) ? 1 : 0;
                const int rr = p - gA * EPB * IN_DIM;
                elA = rr / IN_DIM; iiA = rr - IN_DIM * elA;
                const long be =
                    ((long)(eblk + gA * EPB + elA) * IN_DIM + iiA) * T_STEPS + t0;
                if (isb) {
                    const float4* q = (const float4*)((const unsigned short*)x + be);
                    fbA[0] = q[0]; if (ntS > 8) fbA[1] = q[1];
                } else {
                    const float4* q = (const float4*)((const float*)x + be);
                    fbA[0] = q[0]; fbA[1] = q[1];
                    if (ntS > 8) { fbA[2] = q[2]; fbA[3] = q[3]; }
                }
            }
            if (hasB) {
                const int p = tid + 512;
                gB = 1;                               // 512+tid >= 416 always
                const int rr = p - EPB * IN_DIM;
                elB = rr / IN_DIM; iiB = rr - IN_DIM * elB;
                const long be =
                    ((long)(eblk + EPB + elB) * IN_DIM + iiB) * T_STEPS + t0;
                if (isb) {
                    const float4* q = (const float4*)((const unsigned short*)x + be);
                    fbB[0] = q[0]; if (ntS > 8) fbB[1] = q[1];
                } else {
                    const float4* q = (const float4*)((const float*)x + be);
                    fbB[0] = q[0]; fbB[1] = q[1];
                    if (ntS > 8) { fbB[2] = q[2]; fbB[3] = q[3]; }
                }
            }
        }

        // ---- hoisted LDS reads ----
        const f16x8 h1f0 = *(const f16x8*)&H1T[grp][pp][ecol][g4 * 8];
        const f16x8 h1f1 = *(const f16x8*)&H1T[grp][pp][ecol][32 + g4 * 8];
        f16x8 h2f = {};
        if (role < 2) h2f = *(const f16x8*)&H2T[grp][pc][ecol][g4 * 8]; // h2[s-2]
        f16x8 xf = {};
        if (s + 1 < T_STEPS) {
            const int sn = s + 1;
            xf = *(const f16x8*)&Xst[grp][(sn >> 4) & 1][sn & 15][ecol][g4 * 8];
        }

        // ---- all MFMA blocks first ----
        f32x4 gt1[4], gt2[4];
        if (s < T_STEPS) {
#pragma unroll
            for (int gi = 0; gi < 4; ++gi) {
                f32x4 t0 = MFMA(Whh1A[gi][0], h1f0, xgc[gi]);   // C-init = xg+bias
                gt1[gi]  = MFMA(Whh1A[gi][1], h1f1, t0);
            }
        }
        if (role < 2 && s >= 1) {
#pragma unroll
            for (int gi = 0; gi < 4; ++gi) {
                f32x4 t0 = MFMA(Wih2A[gi][0], h1f0, b2C[gi]);
                t0       = MFMA(Wih2A[gi][1], h1f1, t0);
                gt2[gi]  = MFMA(Whh2A[gi], h2f, t0);
            }
        }
        if (s + 1 < T_STEPS) {          // xg[s+1]; overwrites xgc AFTER gt1 use
#pragma unroll
            for (int gi = 0; gi < 4; ++gi) xgc[gi] = MFMA(Wih1A[gi], xf, b1C[gi]);
        }

        // ---- activations ----
        if (s < T_STEPS) {
            f16x4 hh;
#pragma unroll
            for (int jj = 0; jj < 4; ++jj)            // unit 16*role + 4*g4 + jj
                hh[jj] = (f16)lstm_act(gt1[0][jj], gt1[1][jj],
                                       gt1[2][jj], gt1[3][jj], c1[jj]);
            *(f16x4*)&H1T[grp][pc][ecol][16 * role + g4 * 4] = hh;
        }
        if (role < 2 && s >= 1) {
            f16x4 hh;
#pragma unroll
            for (int jj = 0; jj < 4; ++jj)
                hh[jj] = (f16)lstm_act(gt2[0][jj], gt2[1][jj],
                                       gt2[2][jj], gt2[3][jj], c2[jj]);
            *(f16x4*)&H2T[grp][pp][ecol][16 * role + g4 * 4] = hh;   // h2[s-1]
        }

        // ---- stage writes LATE (dead buffer; HBM latency hidden above) ----
        if (doStage) {
            const int c = (s >> 4) + 1, bf = c & 1;
#pragma unroll
            for (int t = 0; t < CH; ++t) if (t < ntS) {
                float v;
                if (isb) {
                    unsigned int u =
                        __builtin_bit_cast(unsigned int, fbA[t >> 3][(t >> 1) & 3]);
                    v = bits2f((t & 1) ? (unsigned short)(u >> 16)
                                       : (unsigned short)(u & 0xffffu));
                } else {
                    v = fbA[t >> 2][t & 3];
                }
                Xst[gA][bf][t][elA][iiA] = (f16)v;
            }
            if (hasB) {
#pragma unroll
                for (int t = 0; t < CH; ++t) if (t < ntS) {
                    float v;
                    if (isb) {
                        unsigned int u =
                            __builtin_bit_cast(unsigned int, fbB[t >> 3][(t >> 1) & 3]);
                        v = bits2f((t & 1) ? (unsigned short)(u >> 16)
                                           : (unsigned short)(u & 0xffffu));
                    } else {
                        v = fbB[t >> 2][t & 3];
                    }
                    Xst[gB][bf][t][elB][iiB] = (f16)v;
                }
            }
        }

        __syncthreads();
    }

    // ---- FC head: h2[T-1] in H2T[g][1] (written at s=1000, pp=1) ----
    {
        const int g = tid >> 8, r = tid & 255;
        const int e = r >> 4, o = r & 15;
        float ss = ldv(b_fc1, o, isb);
#pragma unroll 8
        for (int k = 0; k < 32; ++k)
            ss = fmaf(ldv(w_fc1, o * 32 + k, isb), (float)H2T[g][1][e][k], ss);
        f1s[g][e][o] = fmaxf(ss, 0.f);
    }
    __syncthreads();
    if (tid < 320) {
        const int g = tid / 160, r = tid - g * 160;
        const int e = r / 10, o = r - e * 10;
        float ss = ldv(b_fc2, o, isb);
#pragma unroll
        for (int k = 0; k < 16; ++k)
            ss = fmaf(ldv(w_fc2, o * 16 + k, isb), f1s[g][e][k], ss);
        const long oi = (long)(eblk + g * EPB + e) * 10 + o;
        if (isb) ((bf16*)out)[oi] = __float2bfloat16(ss);
        else     ((float*)out)[oi] = ss;
    }
}

extern "C" void kernel_launch(void* const* d_in, const int* in_sizes, int n_in,
                              void* d_out, int out_size, void* d_ws, size_t ws_size,
                              hipStream_t stream) {
    lstm_fused<<<dim3(512 / (2 * EPB)), dim3(512), 0, stream>>>(
        d_in[0], d_in[1], d_in[2], d_in[3], d_in[4],
        d_in[5], d_in[6], d_in[7], d_in[8],
        d_in[9], d_in[10], d_in[11], d_in[12], d_out);
}

// Round 5
// 825.762 us; speedup vs baseline: 1.8261x; 1.6177x over previous
//
#include <hip/hip_runtime.h>
#include <hip/hip_bf16.h>

// AudioLSTM fused persistent kernel, v13: 16-WAVE ROLE-SPECIALIZED BLOCKS.
// B=512, T=1000, IN=26, H1=64, H2=32, FC 32->16->10.
// 32 blocks x 1024 threads (16 waves), ONE 16-elem group per block.
// v12 post-mortem: per-SIMD issue ~1700cy/step (acts at quarter-rate trans
// dominate) + lockstep barrier pairing -> tau 3200cy. v13 spreads the group
// over 16 waves (4/SIMD, phase-diverse roles) and un-unions weight regs:
//   waves 0-3 : LSTM1 unit-group r (8 MFMA + 4 acts/lane). xg comes from LDS
//               (XG ring) as the MFMA C-init -> recurrent chain minimal.
//   waves 4-7 : xg[s+1] = W_ih1 X (4 MFMA) -> XG[pp]. Off the serial chain.
//   waves 8-9 : LSTM2 (self-contained: gate->act->gate circularity forbids
//               cross-wave delegation without halving its rate).
//   waves 10-15: x chunk staging (CH=16) + spare.
// Weight arrays UNIONED across roles (W8/W4/C4 = 64 VGPR) -- v12 spilled
// (WRITE_SIZE 292KB) from the 128-reg weight union. One barrier per step.
// Math identical to v11/v12: f16 MFMA frags, prescaled gates, pair-rcp acts.

typedef __hip_bfloat16 bf16;
typedef _Float16 f16;
typedef _Float16 f16x8 __attribute__((ext_vector_type(8)));
typedef _Float16 f16x4 __attribute__((ext_vector_type(4)));
typedef float    f32x4 __attribute__((ext_vector_type(4)));

#define T_STEPS 1000
#define IN_DIM  26
#define EPB     16      // batch elems per block/group
#define CH      16      // staged x chunk length (timesteps)
#define H1P     72      // padded h1 row (f16): 144B
#define H2P     40      // padded h2 row (f16): 80B
#define XP      40      // padded Xst row (f16): 80B, 16B-aligned rows

#define NL2E  -1.4426950408889634f   // -log2(e): i,f,o gate prescale
#define N2L2E -2.8853900817779268f   // -2log2(e): g gate prescale

__device__ __forceinline__ float bits2f(unsigned short h) {
    return __uint_as_float(((unsigned int)h) << 16);
}
__device__ __forceinline__ float ldv(const void* p, long i, bool isb) {
    return isb ? bits2f(((const unsigned short*)p)[i]) : ((const float*)p)[i];
}
__device__ __forceinline__ float rcp_(float x) { return __builtin_amdgcn_rcpf(x); }
__device__ __forceinline__ float ex2_(float x) { return __builtin_amdgcn_exp2f(x); }

// Prescaled pre-activations (yi=-log2e*pi, yg=-2log2e*pg, ...).
// Updates c, returns h = sigm(o)*tanh(c). 5 exp2 + 3 rcp + ~13 VALU.
__device__ __forceinline__ float lstm_act(float yi, float yf, float yg,
                                          float yo, float& c) {
    const float A  = ex2_(yi), F = ex2_(yf), B = ex2_(yg), O = ex2_(yo);
    const float a1 = 1.f + A, f1 = 1.f + F, b1 = 1.f + B, o1 = 1.f + O;
    const float ig = (2.f - b1) * rcp_(a1 * b1);     // sigm(i)*tanh(g)
    c = fmaf(rcp_(f1), c, ig);                       // f*c + i*g
    const float C2  = ex2_(N2L2E * c);               // e^(-2c)
    const float c1p = 1.f + C2;
    return (2.f - c1p) * rcp_(o1 * c1p);             // sigm(o)*tanh(c)
}

#define MFMA(a, b, c) __builtin_amdgcn_mfma_f32_16x16x32_f16((a), (b), (c), 0, 0, 0)

__global__
__attribute__((amdgpu_flat_work_group_size(1024, 1024), amdgpu_waves_per_eu(4, 4)))
void lstm_fused(const void* __restrict__ x,
                const void* __restrict__ w_ih1, const void* __restrict__ w_hh1,
                const void* __restrict__ b_ih1, const void* __restrict__ b_hh1,
                const void* __restrict__ w_ih2, const void* __restrict__ w_hh2,
                const void* __restrict__ b_ih2, const void* __restrict__ b_hh2,
                const void* __restrict__ w_fc1, const void* __restrict__ b_fc1,
                const void* __restrict__ w_fc2, const void* __restrict__ b_fc2,
                void* __restrict__ out)
{
    const int tid  = threadIdx.x;      // 0..1023
    const int lane = tid & 63;
    const int wv   = tid >> 6;         // 0..15
    const int ecol = lane & 15;        // MFMA N-col = elem within group
    const int g4   = lane >> 4;        // lane group 0..3
    const int r15  = lane & 15;
    const int e0   = blockIdx.x * EPB;

    __shared__ __align__(16) f16    Xst[2][CH][EPB][XP];  // x chunks (B-frag)
    __shared__ __align__(16) f16    H1T[2][EPB][H1P];     // h1 dbuf by parity
    __shared__ __align__(16) f16    H2T[2][EPB][H2P];     // h2 dbuf by parity
    __shared__ __align__(16) float4 XG[2][1024];          // xg ring: f32x4/slot
    __shared__ __align__(16) float  f1s[EPB][16];

    // ---- runtime dtype detection (uniform): w_ih1 ~ U(-1/8,1/8) ----
    bool isb = true;
    {
        const unsigned short* wu = (const unsigned short*)w_ih1;
        for (int k = 0; k < 64; ++k) {
            float v = fabsf(bits2f(wu[k]));
            if (!(v <= 0.1251f)) isb = false;
        }
    }

    // ---- zero LDS (x k-pad, h pads, h1[-1]=h2[-1]=0; XG fully written) ----
    {
        float4 z; z.x = z.y = z.z = z.w = 0.f;
        float4* p = (float4*)&Xst[0][0][0][0];
        for (int k = tid; k < (int)(sizeof(Xst) / 16); k += 1024) p[k] = z;
        float4* q = (float4*)&H1T[0][0][0];
        for (int k = tid; k < (int)(sizeof(H1T) / 16); k += 1024) q[k] = z;
        float4* r = (float4*)&H2T[0][0][0];
        for (int k = tid; k < (int)(sizeof(H2T) / 16); k += 1024) r[k] = z;
    }

    // ---- role-unioned weight fragments (A-frag: row=lane&15, k=8*g4+j) ----
    // role0 (wv0-3): W8 = Whh1 of unit-group r. role1 (wv4-7): W4=Wih1, C4=b1.
    // wv8-9: W8=Wih2, W4=Whh2, C4=b2.  Union = 64 VGPR.
    f16x8 W8[8]; f16x8 W4[4]; f32x4 C4[4];
    const int rr4 = wv & 3;
    if (wv < 4) {                       // LSTM1 hh: rows gi*64 + 16*r + r15
#pragma unroll
        for (int gi = 0; gi < 4; ++gi) {
            const float sc = (gi == 2) ? N2L2E : NL2E;
            const int R = gi * 64 + 16 * rr4 + r15;
#pragma unroll
            for (int k0 = 0; k0 < 2; ++k0)
#pragma unroll
                for (int jj = 0; jj < 8; ++jj)
                    W8[gi * 2 + k0][jj] =
                        (f16)(sc * ldv(w_hh1, R * 64 + k0 * 32 + g4 * 8 + jj, isb));
        }
    } else if (wv < 8) {                // xg: W_ih1 rows gi*64 + 16*r + r15
#pragma unroll
        for (int gi = 0; gi < 4; ++gi) {
            const float sc = (gi == 2) ? N2L2E : NL2E;
            const int R = gi * 64 + 16 * rr4 + r15;
#pragma unroll
            for (int jj = 0; jj < 8; ++jj) {
                const int k = g4 * 8 + jj;
                W4[gi][jj] =
                    (f16)(k < IN_DIM ? sc * ldv(w_ih1, R * IN_DIM + k, isb) : 0.f);
            }
#pragma unroll
            for (int jj = 0; jj < 4; ++jj) {
                const int Rc = gi * 64 + 16 * rr4 + g4 * 4 + jj;
                C4[gi][jj] = sc * (ldv(b_ih1, Rc, isb) + ldv(b_hh1, Rc, isb));
            }
        }
    } else if (wv < 10) {               // LSTM2 half = wv&1: rows gi*32+16h+r15
        const int hf = wv & 1;
#pragma unroll
        for (int gi = 0; gi < 4; ++gi) {
            const float sc = (gi == 2) ? N2L2E : NL2E;
            const int R = gi * 32 + 16 * hf + r15;
#pragma unroll
            for (int k0 = 0; k0 < 2; ++k0)
#pragma unroll
                for (int jj = 0; jj < 8; ++jj)
                    W8[gi * 2 + k0][jj] =
                        (f16)(sc * ldv(w_ih2, R * 64 + k0 * 32 + g4 * 8 + jj, isb));
#pragma unroll
            for (int jj = 0; jj < 8; ++jj)
                W4[gi][jj] = (f16)(sc * ldv(w_hh2, R * 32 + g4 * 8 + jj, isb));
#pragma unroll
            for (int jj = 0; jj < 4; ++jj) {
                const int Rc = gi * 32 + 16 * hf + g4 * 4 + jj;
                C4[gi][jj] = sc * (ldv(b_ih2, Rc, isb) + ldv(b_hh2, Rc, isb));
            }
        }
    }

    __syncthreads();   // LDS zeroed before staging overwrites i<26

    // one staged row: Xst[c&1][0..nt)[e][i] <- x[e0+e][i][c*CH .. +nt)
    auto stageRow = [&](int p, int c) {
        const int t0 = c * CH;
        const int nt = (T_STEPS - t0 < CH) ? (T_STEPS - t0) : CH;
        const int e = p / IN_DIM, i = p - e * IN_DIM;
        const long gb = ((long)(e0 + e) * IN_DIM + i) * T_STEPS + t0;
        float4 fb[4];
        if (isb) {
            const float4* q = (const float4*)((const unsigned short*)x + gb);
            fb[0] = q[0]; if (nt > 8) fb[1] = q[1];
        } else {
            const float4* q = (const float4*)((const float*)x + gb);
            fb[0] = q[0]; fb[1] = q[1];
            if (nt > 8) { fb[2] = q[2]; fb[3] = q[3]; }
        }
#pragma unroll
        for (int t = 0; t < CH; ++t) if (t < nt) {
            float v;
            if (isb) {
                unsigned int u =
                    __builtin_bit_cast(unsigned int, fb[t >> 3][(t >> 1) & 3]);
                v = bits2f((t & 1) ? (unsigned short)(u >> 16)
                                   : (unsigned short)(u & 0xffffu));
            } else {
                v = fb[t >> 2][t & 3];
            }
            Xst[c & 1][t][e][i] = (f16)v;
        }
    };

    if (tid < EPB * IN_DIM) stageRow(tid, 0);       // chunk 0, all hands
    __syncthreads();

    // xg[0] -> XG[0] (xg waves)
    if (wv >= 4 && wv < 8) {
        const f16x8 xf = *(const f16x8*)&Xst[0][0][ecol][g4 * 8];
#pragma unroll
        for (int gi = 0; gi < 4; ++gi) {
            f32x4 v = MFMA(W4[gi], xf, C4[gi]);
            *(f32x4*)&XG[0][((rr4 * 4 + gi) * 4 + g4) * 16 + ecol] = v;
        }
    }
    __syncthreads();

    // chain-critical waves get issue priority (T5: role-diverse waves exist)
    if (wv < 4 || wv == 8 || wv == 9) __builtin_amdgcn_s_setprio(1);

    float cst[4] = {0.f, 0.f, 0.f, 0.f};   // c1 (wv0-3) or c2 (wv8-9)

    for (int s = 0; s <= T_STEPS; ++s) {
        const int pc = s & 1, pp = pc ^ 1;

        if (wv < 4) {
            // ======== LSTM1 unit-group rr4: the recurrent critical path ====
            if (s < T_STEPS) {
                const f16x8 h1f0 = *(const f16x8*)&H1T[pp][ecol][g4 * 8];
                const f16x8 h1f1 = *(const f16x8*)&H1T[pp][ecol][32 + g4 * 8];
                f32x4 gt[4];
#pragma unroll
                for (int gi = 0; gi < 4; ++gi) {
                    const f32x4 xgc =
                        *(const f32x4*)&XG[pc][((rr4 * 4 + gi) * 4 + g4) * 16 + ecol];
                    f32x4 t0 = MFMA(W8[gi * 2 + 0], h1f0, xgc);  // C = xg+bias
                    gt[gi]   = MFMA(W8[gi * 2 + 1], h1f1, t0);
                }
                f16x4 hh;
#pragma unroll
                for (int jj = 0; jj < 4; ++jj)        // unit 16*rr4 + 4*g4 + jj
                    hh[jj] = (f16)lstm_act(gt[0][jj], gt[1][jj],
                                           gt[2][jj], gt[3][jj], cst[jj]);
                *(f16x4*)&H1T[pc][ecol][16 * rr4 + g4 * 4] = hh;
            }
        } else if (wv < 8) {
            // ======== xg[s+1] -> XG[pp] (dead buffer, barrier-separated) ===
            if (s + 1 < T_STEPS) {
                const int sn = s + 1;
                const f16x8 xf =
                    *(const f16x8*)&Xst[(sn >> 4) & 1][sn & 15][ecol][g4 * 8];
#pragma unroll
                for (int gi = 0; gi < 4; ++gi) {
                    f32x4 v = MFMA(W4[gi], xf, C4[gi]);
                    *(f32x4*)&XG[pp][((rr4 * 4 + gi) * 4 + g4) * 16 + ecol] = v;
                }
            }
        } else if (wv < 10) {
            // ======== LSTM2 step s-1 (half=wv&1): h1[s-1], h2[s-2] =========
            if (s >= 1) {
                const int hf = wv & 1;
                const f16x8 h1f0 = *(const f16x8*)&H1T[pp][ecol][g4 * 8];
                const f16x8 h1f1 = *(const f16x8*)&H1T[pp][ecol][32 + g4 * 8];
                const f16x8 h2f  = *(const f16x8*)&H2T[pc][ecol][g4 * 8];
                f32x4 gt[4];
#pragma unroll
                for (int gi = 0; gi < 4; ++gi) {
                    f32x4 t0 = MFMA(W8[gi * 2 + 0], h1f0, C4[gi]);
                    t0       = MFMA(W8[gi * 2 + 1], h1f1, t0);
                    gt[gi]   = MFMA(W4[gi], h2f, t0);
                }
                f16x4 hh;
#pragma unroll
                for (int jj = 0; jj < 4; ++jj)        // unit 16*hf + 4*g4 + jj
                    hh[jj] = (f16)lstm_act(gt[0][jj], gt[1][jj],
                                           gt[2][jj], gt[3][jj], cst[jj]);
                *(f16x4*)&H2T[pp][ecol][16 * hf + g4 * 4] = hh;   // h2[s-1]
            }
        } else {
            // ======== staging waves (wv10-15): next x chunk every CH steps =
            if ((s & (CH - 1)) == 0 && s + CH < T_STEPS) {
                const int c = (s >> 4) + 1;
                const int p = tid - 640;              // 0..383
                stageRow(p, c);
                if (p < EPB * IN_DIM - 384) stageRow(p + 384, c);
            }
        }

        __syncthreads();
    }

    // ---- FC head: h2[T-1] in H2T[1] (s=1000 even -> pp=1) ----
    if (tid < EPB * 16) {
        const int e = tid >> 4, o = tid & 15;
        float ss = ldv(b_fc1, o, isb);
#pragma unroll 8
        for (int k = 0; k < 32; ++k)
            ss = fmaf(ldv(w_fc1, o * 32 + k, isb), (float)H2T[1][e][k], ss);
        f1s[e][o] = fmaxf(ss, 0.f);
    }
    __syncthreads();
    if (tid < EPB * 10) {
        const int e = tid / 10, o = tid - e * 10;
        float ss = ldv(b_fc2, o, isb);
#pragma unroll
        for (int k = 0; k < 16; ++k)
            ss = fmaf(ldv(w_fc2, o * 16 + k, isb), f1s[e][k], ss);
        const long oi = (long)(e0 + e) * 10 + o;
        if (isb) ((bf16*)out)[oi] = __float2bfloat16(ss);
        else     ((float*)out)[oi] = ss;
    }
}

extern "C" void kernel_launch(void* const* d_in, const int* in_sizes, int n_in,
                              void* d_out, int out_size, void* d_ws, size_t ws_size,
                              hipStream_t stream) {
    lstm_fused<<<dim3(512 / EPB), dim3(1024), 0, stream>>>(
        d_in[0], d_in[1], d_in[2], d_in[3], d_in[4],
        d_in[5], d_in[6], d_in[7], d_in[8],
        d_in[9], d_in[10], d_in[11], d_in[12], d_out);
}

// Round 6
// 821.679 us; speedup vs baseline: 1.8352x; 1.0050x over previous
//
#include <hip/hip_runtime.h>
#include <hip/hip_bf16.h>

// AudioLSTM fused persistent kernel, v14: 8-WAVE, REGISTER-xg, SMOOTH STAGING.
// B=512, T=1000, IN=26, H1=64, H2=32, FC 32->16->10.
// 32 blocks x 512 threads (8 waves), one 16-elem group per block.
// v13 post-mortem (826us, 1880cy/step): ~45% stall; XG LDS round-trip on the
// LSTM1 critical chain + barrier-aligned stall phases + SIMD0/1 issue pole.
// v14: (1) xg computed IN the LSTM1 waves (v11 pattern) -> xgc registers feed
//      next step's MFMA C-init; XG buffer (32KB) + xg waves deleted; chain
//      loses a post-barrier ds_read. (2) 8 waves (2/SIMD): wv0-3 LSTM1+xg,
//      wv4-5 LSTM2, wv6-7 staging -> less barrier skew + LDS burst.
//      (3) staging smoothed to 26 rows/step (no 416-row burst), shifted one
//      step early so last slice lands a barrier before first read.
// Math identical to v11/v13: f16 MFMA frags, prescaled gates, pair-rcp acts.

typedef __hip_bfloat16 bf16;
typedef _Float16 f16;
typedef _Float16 f16x8 __attribute__((ext_vector_type(8)));
typedef _Float16 f16x4 __attribute__((ext_vector_type(4)));
typedef float    f32x4 __attribute__((ext_vector_type(4)));

#define T_STEPS 1000
#define IN_DIM  26
#define EPB     16      // batch elems per block/group
#define CH      16      // staged x chunk length (timesteps)
#define NCHUNK  62      // last chunk index = (T_STEPS-1)/CH
#define H1P     72      // padded h1 row (f16): 144B
#define H2P     40      // padded h2 row (f16): 80B
#define XP      40      // padded Xst row (f16): 80B

#define NL2E  -1.4426950408889634f   // -log2(e): i,f,o gate prescale
#define N2L2E -2.8853900817779268f   // -2log2(e): g gate prescale

__device__ __forceinline__ float bits2f(unsigned short h) {
    return __uint_as_float(((unsigned int)h) << 16);
}
__device__ __forceinline__ float ldv(const void* p, long i, bool isb) {
    return isb ? bits2f(((const unsigned short*)p)[i]) : ((const float*)p)[i];
}
__device__ __forceinline__ float rcp_(float x) { return __builtin_amdgcn_rcpf(x); }
__device__ __forceinline__ float ex2_(float x) { return __builtin_amdgcn_exp2f(x); }

// Prescaled pre-activations (yi=-log2e*pi, yg=-2log2e*pg, ...).
// Updates c, returns h = sigm(o)*tanh(c). 5 exp2 + 3 rcp + ~13 VALU.
__device__ __forceinline__ float lstm_act(float yi, float yf, float yg,
                                          float yo, float& c) {
    const float A  = ex2_(yi), F = ex2_(yf), B = ex2_(yg), O = ex2_(yo);
    const float a1 = 1.f + A, f1 = 1.f + F, b1 = 1.f + B, o1 = 1.f + O;
    const float ig = (2.f - b1) * rcp_(a1 * b1);     // sigm(i)*tanh(g)
    c = fmaf(rcp_(f1), c, ig);                       // f*c + i*g
    const float C2  = ex2_(N2L2E * c);               // e^(-2c)
    const float c1p = 1.f + C2;
    return (2.f - c1p) * rcp_(o1 * c1p);             // sigm(o)*tanh(c)
}

#define MFMA(a, b, c) __builtin_amdgcn_mfma_f32_16x16x32_f16((a), (b), (c), 0, 0, 0)

__global__
__attribute__((amdgpu_flat_work_group_size(512, 512), amdgpu_waves_per_eu(2, 2)))
void lstm_fused(const void* __restrict__ x,
                const void* __restrict__ w_ih1, const void* __restrict__ w_hh1,
                const void* __restrict__ b_ih1, const void* __restrict__ b_hh1,
                const void* __restrict__ w_ih2, const void* __restrict__ w_hh2,
                const void* __restrict__ b_ih2, const void* __restrict__ b_hh2,
                const void* __restrict__ w_fc1, const void* __restrict__ b_fc1,
                const void* __restrict__ w_fc2, const void* __restrict__ b_fc2,
                void* __restrict__ out)
{
    const int tid  = threadIdx.x;      // 0..511
    const int lane = tid & 63;
    const int wv   = tid >> 6;         // 0..7
    const int ecol = lane & 15;        // MFMA N-col = elem within group
    const int g4   = lane >> 4;        // lane group 0..3
    const int r15  = lane & 15;
    const int e0   = blockIdx.x * EPB;

    __shared__ __align__(16) f16   Xst[2][CH][EPB][XP];  // 40960 B
    __shared__ __align__(16) f16   H1T[2][EPB][H1P];     // 4608 B
    __shared__ __align__(16) f16   H2T[2][EPB][H2P];     // 2560 B
    __shared__ __align__(16) float f1s[EPB][16];         // 1024 B

    // ---- runtime dtype detection (uniform): w_ih1 ~ U(-1/8,1/8) ----
    bool isb = true;
    {
        const unsigned short* wu = (const unsigned short*)w_ih1;
        for (int k = 0; k < 64; ++k) {
            float v = fabsf(bits2f(wu[k]));
            if (!(v <= 0.1251f)) isb = false;
        }
    }

    // ---- zero LDS (x k-pad, h pads, h1[-1]=h2[-1]=0) ----
    {
        float4 z; z.x = z.y = z.z = z.w = 0.f;
        float4* p = (float4*)&Xst[0][0][0][0];
        for (int k = tid; k < (int)(sizeof(Xst) / 16); k += 512) p[k] = z;
        float4* q = (float4*)&H1T[0][0][0];
        for (int k = tid; k < (int)(sizeof(H1T) / 16); k += 512) q[k] = z;
        float4* r = (float4*)&H2T[0][0][0];
        for (int k = tid; k < (int)(sizeof(H2T) / 16); k += 512) r[k] = z;
    }

    // ---- role weight fragments (A-frag: row = lane&15, k = 8*g4+j) ----
    // wv0-3 (LSTM1 unit-group wv): W8 = Whh1 (2 K-tiles x 4 gates),
    //   W4 = Wih1, C4 = prescaled bias (MFMA C-init layout).
    // wv4-5 (LSTM2 half wv-4):     W8 = Wih2, W4 = Whh2, C4 = bias2.
    f16x8 W8[8]; f16x8 W4[4]; f32x4 C4[4];
    if (wv < 4) {
#pragma unroll
        for (int gi = 0; gi < 4; ++gi) {
            const float sc = (gi == 2) ? N2L2E : NL2E;
            const int R = gi * 64 + 16 * wv + r15;
#pragma unroll
            for (int k0 = 0; k0 < 2; ++k0)
#pragma unroll
                for (int jj = 0; jj < 8; ++jj)
                    W8[gi * 2 + k0][jj] =
                        (f16)(sc * ldv(w_hh1, R * 64 + k0 * 32 + g4 * 8 + jj, isb));
#pragma unroll
            for (int jj = 0; jj < 8; ++jj) {
                const int k = g4 * 8 + jj;
                W4[gi][jj] =
                    (f16)(k < IN_DIM ? sc * ldv(w_ih1, R * IN_DIM + k, isb) : 0.f);
            }
#pragma unroll
            for (int jj = 0; jj < 4; ++jj) {
                const int Rc = gi * 64 + 16 * wv + g4 * 4 + jj;
                C4[gi][jj] = sc * (ldv(b_ih1, Rc, isb) + ldv(b_hh1, Rc, isb));
            }
        }
    } else if (wv < 6) {
        const int hf = wv - 4;
#pragma unroll
        for (int gi = 0; gi < 4; ++gi) {
            const float sc = (gi == 2) ? N2L2E : NL2E;
            const int R = gi * 32 + 16 * hf + r15;
#pragma unroll
            for (int k0 = 0; k0 < 2; ++k0)
#pragma unroll
                for (int jj = 0; jj < 8; ++jj)
                    W8[gi * 2 + k0][jj] =
                        (f16)(sc * ldv(w_ih2, R * 64 + k0 * 32 + g4 * 8 + jj, isb));
#pragma unroll
            for (int jj = 0; jj < 8; ++jj)
                W4[gi][jj] = (f16)(sc * ldv(w_hh2, R * 32 + g4 * 8 + jj, isb));
#pragma unroll
            for (int jj = 0; jj < 4; ++jj) {
                const int Rc = gi * 32 + 16 * hf + g4 * 4 + jj;
                C4[gi][jj] = sc * (ldv(b_ih2, Rc, isb) + ldv(b_hh2, Rc, isb));
            }
        }
    }

    __syncthreads();   // LDS zeroed before staging overwrites i<26

    // stage one (e,i) row of chunk c: 16 timesteps, wide loads
    auto stageRow = [&](int p, int c) {
        const int t0 = c * CH;
        const int nt = (T_STEPS - t0 < CH) ? (T_STEPS - t0) : CH;
        const int e = p / IN_DIM, i = p - e * IN_DIM;
        const long gb = ((long)(e0 + e) * IN_DIM + i) * T_STEPS + t0;
        float4 fb[4];
        if (isb) {
            const float4* q = (const float4*)((const unsigned short*)x + gb);
            fb[0] = q[0]; if (nt > 8) fb[1] = q[1];
        } else {
            const float4* q = (const float4*)((const float*)x + gb);
            fb[0] = q[0]; fb[1] = q[1];
            if (nt > 8) { fb[2] = q[2]; fb[3] = q[3]; }
        }
#pragma unroll
        for (int t = 0; t < CH; ++t) if (t < nt) {
            float v;
            if (isb) {
                unsigned int u =
                    __builtin_bit_cast(unsigned int, fb[t >> 3][(t >> 1) & 3]);
                v = bits2f((t & 1) ? (unsigned short)(u >> 16)
                                   : (unsigned short)(u & 0xffffu));
            } else {
                v = fb[t >> 2][t & 3];
            }
            Xst[c & 1][t][e][i] = (f16)v;
        }
    };

    // prologue: chunk 0 fully (416 rows) + chunk 1 slice 0 (rows 0..25)
    if (tid < EPB * IN_DIM) stageRow(tid, 0);
    if (tid >= 448 && tid < 448 + 26) stageRow(tid - 448, 1);
    __syncthreads();

    // xg[0] into registers (LSTM1 waves; C-layout, prescaled bias folded in)
    f32x4 xgc[4];
    if (wv < 4) {
        const f16x8 xf = *(const f16x8*)&Xst[0][0][ecol][g4 * 8];
#pragma unroll
        for (int gi = 0; gi < 4; ++gi) xgc[gi] = MFMA(W4[gi], xf, C4[gi]);
    }

    if (wv < 6) __builtin_amdgcn_s_setprio(1);   // compute waves get priority

    float cst[4] = {0.f, 0.f, 0.f, 0.f};   // c1 (wv0-3) or c2 (wv4-5)

    for (int s = 0; s <= T_STEPS; ++s) {
        const int pc = s & 1, pp = pc ^ 1;

        if (wv < 4) {
            // ==== LSTM1 unit-group wv (+ own xg pipeline) ====
            if (s < T_STEPS) {
                const f16x8 h1f0 = *(const f16x8*)&H1T[pp][ecol][g4 * 8];
                const f16x8 h1f1 = *(const f16x8*)&H1T[pp][ecol][32 + g4 * 8];
                const bool nx = (s + 1 < T_STEPS);
                f16x8 xf = {};
                if (nx) {
                    const int sn = s + 1;
                    xf = *(const f16x8*)&Xst[(sn >> 4) & 1][sn & 15][ecol][g4 * 8];
                }
                f32x4 gt[4];
#pragma unroll
                for (int gi = 0; gi < 4; ++gi) {
                    f32x4 t0 = MFMA(W8[gi * 2 + 0], h1f0, xgc[gi]);  // C = xg
                    gt[gi]   = MFMA(W8[gi * 2 + 1], h1f1, t0);
                }
                f32x4 xgn[4];
                if (nx) {
#pragma unroll
                    for (int gi = 0; gi < 4; ++gi)
                        xgn[gi] = MFMA(W4[gi], xf, C4[gi]);          // xg[s+1]
                }
                f16x4 hh;
#pragma unroll
                for (int jj = 0; jj < 4; ++jj)        // unit 16*wv + 4*g4 + jj
                    hh[jj] = (f16)lstm_act(gt[0][jj], gt[1][jj],
                                           gt[2][jj], gt[3][jj], cst[jj]);
                *(f16x4*)&H1T[pc][ecol][16 * wv + g4 * 4] = hh;
                if (nx) {
#pragma unroll
                    for (int gi = 0; gi < 4; ++gi) xgc[gi] = xgn[gi];
                }
            }
        } else if (wv < 6) {
            // ==== LSTM2 step s-1 (half wv-4): h1[s-1], h2[s-2] ====
            if (s >= 1) {
                const int hf = wv - 4;
                const f16x8 h1f0 = *(const f16x8*)&H1T[pp][ecol][g4 * 8];
                const f16x8 h1f1 = *(const f16x8*)&H1T[pp][ecol][32 + g4 * 8];
                const f16x8 h2f  = *(const f16x8*)&H2T[pc][ecol][g4 * 8];
                f32x4 gt[4];
#pragma unroll
                for (int gi = 0; gi < 4; ++gi) {
                    f32x4 t0 = MFMA(W8[gi * 2 + 0], h1f0, C4[gi]);
                    t0       = MFMA(W8[gi * 2 + 1], h1f1, t0);
                    gt[gi]   = MFMA(W4[gi], h2f, t0);
                }
                f16x4 hh;
#pragma unroll
                for (int jj = 0; jj < 4; ++jj)        // unit 16*hf + 4*g4 + jj
                    hh[jj] = (f16)lstm_act(gt[0][jj], gt[1][jj],
                                           gt[2][jj], gt[3][jj], cst[jj]);
                *(f16x4*)&H2T[pp][ecol][16 * hf + g4 * 4] = hh;   // h2[s-1]
            }
        } else {
            // ==== staging waves (wv6-7): 26 rows/step, one step ahead ====
            const int s1 = s + 1, c = (s1 >> 4) + 1;
            if (c <= NCHUNK) {
                const int slice = s1 & 15;
                const int p = slice * 26 + (wv - 6) * 13 + lane;
                if (lane < 13) stageRow(p, c);
            }
        }

        __syncthreads();
    }

    // ---- FC head: h2[T-1] in H2T[1] (written at s=1000, pp=1) ----
    if (tid < EPB * 16) {
        const int e = tid >> 4, o = tid & 15;
        float ss = ldv(b_fc1, o, isb);
#pragma unroll 8
        for (int k = 0; k < 32; ++k)
            ss = fmaf(ldv(w_fc1, o * 32 + k, isb), (float)H2T[1][e][k], ss);
        f1s[e][o] = fmaxf(ss, 0.f);
    }
    __syncthreads();
    if (tid < EPB * 10) {
        const int e = tid / 10, o = tid - e * 10;
        float ss = ldv(b_fc2, o, isb);
#pragma unroll
        for (int k = 0; k < 16; ++k)
            ss = fmaf(ldv(w_fc2, o * 16 + k, isb), f1s[e][k], ss);
        const long oi = (long)(e0 + e) * 10 + o;
        if (isb) ((bf16*)out)[oi] = __float2bfloat16(ss);
        else     ((float*)out)[oi] = ss;
    }
}

extern "C" void kernel_launch(void* const* d_in, const int* in_sizes, int n_in,
                              void* d_out, int out_size, void* d_ws, size_t ws_size,
                              hipStream_t stream) {
    lstm_fused<<<dim3(512 / EPB), dim3(512), 0, stream>>>(
        d_in[0], d_in[1], d_in[2], d_in[3], d_in[4],
        d_in[5], d_in[6], d_in[7], d_in[8],
        d_in[9], d_in[10], d_in[11], d_in[12], d_out);
}